// Round 1
// baseline (123.229 us; speedup 1.0000x reference)
//
#include <hip/hip_runtime.h>
#include <hip/hip_bf16.h>
#include <stdint.h>

typedef __bf16 bf16_t;
typedef __bf16 bf16x8 __attribute__((ext_vector_type(8)));
typedef float f32x4 __attribute__((ext_vector_type(4)));

#define NB 2
#define NN 2048
#define ND 1024
#define NH 16
#define DHEAD 64
#define WIN 128

__device__ __forceinline__ void load_lds16(const void* g, void* l) {
  __builtin_amdgcn_global_load_lds(
      (const __attribute__((address_space(1))) uint32_t*)g,
      (__attribute__((address_space(3))) uint32_t*)l, 16, 0, 0);
}

__global__ __launch_bounds__(256) void cast_kernel(const float* __restrict__ in,
                                                   bf16_t* __restrict__ out, int n4) {
  int i = blockIdx.x * 256 + threadIdx.x;
  if (i < n4) {
    float4 v = reinterpret_cast<const float4*>(in)[i];
    union { bf16_t h[4]; uint2 u; } o;
    o.h[0] = (bf16_t)v.x; o.h[1] = (bf16_t)v.y;
    o.h[2] = (bf16_t)v.z; o.h[3] = (bf16_t)v.w;
    reinterpret_cast<uint2*>(out)[i] = o.u;
  }
}

// C[m][n] = sum_k A[m][k] * Bw[n][k], K=1024. 128x128 tile, BK=32, 4 waves 2x2.
__device__ __forceinline__ void gemm_tile(const bf16_t* __restrict__ A,
                                          const bf16_t* __restrict__ Bw,
                                          bf16_t* As, bf16_t* Bs,
                                          int m0, int n0, f32x4 acc[4][4]) {
  const int tid  = threadIdx.x;
  const int lane = tid & 63;
  const int wid  = tid >> 6;
  const int wr = wid >> 1, wc = wid & 1;
  const int lrow = lane & 15, lkg = lane >> 4;
  const int srow = lane >> 2, scol = (lane & 3) * 8;

  for (int k0 = 0; k0 < 1024; k0 += 32) {
#pragma unroll
    for (int i = 0; i < 2; ++i) {
      const int rbase = (wid * 2 + i) * 16;
      load_lds16(A  + (size_t)(m0 + rbase + srow) * 1024 + k0 + scol, As + rbase * 32);
      load_lds16(Bw + (size_t)(n0 + rbase + srow) * 1024 + k0 + scol, Bs + rbase * 32);
    }
    __syncthreads();
    bf16x8 af[4], bf[4];
#pragma unroll
    for (int m = 0; m < 4; ++m)
      af[m] = *reinterpret_cast<const bf16x8*>(As + (wr * 64 + m * 16 + lrow) * 32 + lkg * 8);
#pragma unroll
    for (int n = 0; n < 4; ++n)
      bf[n] = *reinterpret_cast<const bf16x8*>(Bs + (wc * 64 + n * 16 + lrow) * 32 + lkg * 8);
#pragma unroll
    for (int m = 0; m < 4; ++m)
#pragma unroll
      for (int n = 0; n < 4; ++n)
        acc[m][n] = __builtin_amdgcn_mfma_f32_16x16x32_bf16(af[m], bf[n], acc[m][n], 0, 0, 0);
    __syncthreads();
  }
}

__global__ __launch_bounds__(256, 2)
void qkv_gemm(const bf16_t* __restrict__ xb,
              const bf16_t* __restrict__ Wqb, const bf16_t* __restrict__ Wkb,
              const bf16_t* __restrict__ Wvb,
              const float* __restrict__ bq, const float* __restrict__ bk,
              const float* __restrict__ bv,
              bf16_t* __restrict__ Qb, bf16_t* __restrict__ Kb,
              bf16_t* __restrict__ VTb) {
  __shared__ __align__(16) bf16_t As[128 * 32];
  __shared__ __align__(16) bf16_t Bs[128 * 32];
  const int z = blockIdx.z;
  const bf16_t* Bw  = (z == 0) ? Wqb : (z == 1) ? Wkb : Wvb;
  const float* bias = (z == 0) ? bq  : (z == 1) ? bk  : bv;
  const int m0 = blockIdx.y * 128, n0 = blockIdx.x * 128;
  f32x4 acc[4][4] = {};
  gemm_tile(xb, Bw, As, Bs, m0, n0, acc);

  const int lane = threadIdx.x & 63;
  const int wid  = threadIdx.x >> 6;
  const int wr = wid >> 1, wc = wid & 1;
  const int lrow = lane & 15, lkg = lane >> 4;
#pragma unroll
  for (int m = 0; m < 4; ++m)
#pragma unroll
    for (int n = 0; n < 4; ++n)
#pragma unroll
      for (int r = 0; r < 4; ++r) {
        int row = m0 + wr * 64 + m * 16 + lkg * 4 + r;   // token
        int col = n0 + wc * 64 + n * 16 + lrow;          // feature
        float val = acc[m][n][r] + bias[col];
        if (z == 2) {
          VTb[((size_t)((row >> 11) * 1024 + col)) * 2048 + (row & 2047)] = (bf16_t)val;
        } else {
          bf16_t* outp = (z == 0) ? Qb : Kb;
          outp[(size_t)row * 1024 + col] = (bf16_t)val;
        }
      }
}

__global__ __launch_bounds__(256, 2)
void out_gemm(const bf16_t* __restrict__ AOb, const bf16_t* __restrict__ Wob,
              const float* __restrict__ bo, float* __restrict__ Cout) {
  __shared__ __align__(16) bf16_t As[128 * 32];
  __shared__ __align__(16) bf16_t Bs[128 * 32];
  const int m0 = blockIdx.y * 128, n0 = blockIdx.x * 128;
  f32x4 acc[4][4] = {};
  gemm_tile(AOb, Wob, As, Bs, m0, n0, acc);

  const int lane = threadIdx.x & 63;
  const int wid  = threadIdx.x >> 6;
  const int wr = wid >> 1, wc = wid & 1;
  const int lrow = lane & 15, lkg = lane >> 4;
#pragma unroll
  for (int m = 0; m < 4; ++m)
#pragma unroll
    for (int n = 0; n < 4; ++n)
#pragma unroll
      for (int r = 0; r < 4; ++r) {
        int row = m0 + wr * 64 + m * 16 + lkg * 4 + r;
        int col = n0 + wc * 64 + n * 16 + lrow;
        Cout[(size_t)row * 1024 + col] = acc[m][n][r] + bo[col];
      }
}

__global__ __launch_bounds__(256, 2)
void attn_kernel(const bf16_t* __restrict__ Q, const bf16_t* __restrict__ Kb,
                 const bf16_t* __restrict__ VT, bf16_t* __restrict__ AO) {
  const int qt = blockIdx.x, h = blockIdx.y, b = blockIdx.z;
  const int tid = threadIdx.x;
  const int lane = tid & 63;
  const int w = tid >> 6;
  const int q0 = qt * 64;
  const int qrow_base = q0 + w * 16;
  const int lrow = lane & 15, lkg = lane >> 4;
  const int myq = lkg * 4;

  __shared__ __align__(16) bf16_t P_lds[4][16][32];

  const bf16_t* qptr = Q + (size_t)(b * NN + qrow_base + lrow) * ND + h * DHEAD + lkg * 8;
  bf16x8 qf0 = *reinterpret_cast<const bf16x8*>(qptr);
  bf16x8 qf1 = *reinterpret_cast<const bf16x8*>(qptr + 32);

  float m_r[4], l_r[4];
  f32x4 o[4] = {};
#pragma unroll
  for (int r = 0; r < 4; ++r) { m_r[r] = -1e30f; l_r[r] = 0.f; }

  const int kstart = (q0 - WIN > 0) ? (q0 - WIN) : 0;
  const int kend = (q0 + 64 + WIN < NN) ? (q0 + 64 + WIN) : NN;
  const float scale = 0.125f;
  const bf16_t* vbase = VT + (size_t)((b * NH + h) * DHEAD) * NN;

  for (int kc = kstart; kc < kend; kc += 32) {
    f32x4 s[2];
#pragma unroll
    for (int t = 0; t < 2; ++t) {
      const bf16_t* kptr = Kb + (size_t)(b * NN + kc + t * 16 + lrow) * ND + h * DHEAD + lkg * 8;
      bf16x8 kf0 = *reinterpret_cast<const bf16x8*>(kptr);
      bf16x8 kf1 = *reinterpret_cast<const bf16x8*>(kptr + 32);
      f32x4 zz = {};
      zz = __builtin_amdgcn_mfma_f32_16x16x32_bf16(qf0, kf0, zz, 0, 0, 0);
      zz = __builtin_amdgcn_mfma_f32_16x16x32_bf16(qf1, kf1, zz, 0, 0, 0);
      s[t] = zz;
    }
    float v[2][4], mm[4];
    bool msk[2][4];
#pragma unroll
    for (int r = 0; r < 4; ++r) {
      int qrow = qrow_base + myq + r;
      int d0 = qrow - (kc + lrow);
      int d1 = qrow - (kc + 16 + lrow);
      msk[0][r] = (d0 < -WIN) || (d0 > WIN);
      msk[1][r] = (d1 < -WIN) || (d1 > WIN);
      v[0][r] = msk[0][r] ? -1e30f : s[0][r] * scale;
      v[1][r] = msk[1][r] ? -1e30f : s[1][r] * scale;
      mm[r] = fmaxf(v[0][r], v[1][r]);
    }
#pragma unroll
    for (int d = 1; d < 16; d <<= 1)
#pragma unroll
      for (int r = 0; r < 4; ++r)
        mm[r] = fmaxf(mm[r], __shfl_xor(mm[r], d, 64));
    float corr[4], rs[4], p[2][4];
#pragma unroll
    for (int r = 0; r < 4; ++r) {
      float mn = fmaxf(m_r[r], mm[r]);
      corr[r] = __expf(m_r[r] - mn);
      m_r[r] = mn;
      p[0][r] = msk[0][r] ? 0.f : __expf(v[0][r] - mn);
      p[1][r] = msk[1][r] ? 0.f : __expf(v[1][r] - mn);
      rs[r] = p[0][r] + p[1][r];
    }
#pragma unroll
    for (int d = 1; d < 16; d <<= 1)
#pragma unroll
      for (int r = 0; r < 4; ++r)
        rs[r] += __shfl_xor(rs[r], d, 64);
#pragma unroll
    for (int r = 0; r < 4; ++r)
      l_r[r] = l_r[r] * corr[r] + rs[r];
#pragma unroll
    for (int f = 0; f < 4; ++f)
#pragma unroll
      for (int r = 0; r < 4; ++r)
        o[f][r] *= corr[r];
#pragma unroll
    for (int t = 0; t < 2; ++t)
#pragma unroll
      for (int r = 0; r < 4; ++r)
        P_lds[w][myq + r][t * 16 + lrow] = (bf16_t)p[t][r];
    __syncthreads();
    bf16x8 pa = *reinterpret_cast<const bf16x8*>(&P_lds[w][lrow][lkg * 8]);
#pragma unroll
    for (int f = 0; f < 4; ++f) {
      const bf16_t* vp = vbase + (size_t)(f * 16 + lrow) * NN + kc + lkg * 8;
      bf16x8 vf = *reinterpret_cast<const bf16x8*>(vp);
      o[f] = __builtin_amdgcn_mfma_f32_16x16x32_bf16(pa, vf, o[f], 0, 0, 0);
    }
    __syncthreads();
  }

  float inv[4];
#pragma unroll
  for (int r = 0; r < 4; ++r) inv[r] = 1.0f / l_r[r];
#pragma unroll
  for (int f = 0; f < 4; ++f)
#pragma unroll
    for (int r = 0; r < 4; ++r) {
      int row = b * NN + qrow_base + myq + r;
      int col = h * DHEAD + f * 16 + lrow;
      AO[(size_t)row * ND + col] = (bf16_t)(o[f][r] * inv[r]);
    }
}

extern "C" void kernel_launch(void* const* d_in, const int* in_sizes, int n_in,
                              void* d_out, int out_size, void* d_ws, size_t ws_size,
                              hipStream_t stream) {
  const float* x  = (const float*)d_in[0];
  const float* Wq = (const float*)d_in[1];
  const float* bq = (const float*)d_in[2];
  const float* Wk = (const float*)d_in[3];
  const float* bk = (const float*)d_in[4];
  const float* Wv = (const float*)d_in[5];
  const float* bv = (const float*)d_in[6];
  const float* Wo = (const float*)d_in[7];
  const float* bo = (const float*)d_in[8];
  float* out = (float*)d_out;

  bf16_t* ws  = (bf16_t*)d_ws;
  bf16_t* xb  = ws;
  bf16_t* Wqb = xb  + 4194304;
  bf16_t* Wkb = Wqb + 1048576;
  bf16_t* Wvb = Wkb + 1048576;
  bf16_t* Wob = Wvb + 1048576;
  bf16_t* Qb  = Wob + 1048576;
  bf16_t* Kb  = Qb  + 4194304;
  bf16_t* VTb = Kb  + 4194304;
  bf16_t* AOb = VTb + 4194304;

  cast_kernel<<<4096, 256, 0, stream>>>(x,  xb,  1048576);
  cast_kernel<<<1024, 256, 0, stream>>>(Wq, Wqb, 262144);
  cast_kernel<<<1024, 256, 0, stream>>>(Wk, Wkb, 262144);
  cast_kernel<<<1024, 256, 0, stream>>>(Wv, Wvb, 262144);
  cast_kernel<<<1024, 256, 0, stream>>>(Wo, Wob, 262144);

  qkv_gemm<<<dim3(8, 32, 3), 256, 0, stream>>>(xb, Wqb, Wkb, Wvb, bq, bk, bv, Qb, Kb, VTb);
  attn_kernel<<<dim3(NN / 64, NH, NB), 256, 0, stream>>>(Qb, Kb, VTb, AOb);
  out_gemm<<<dim3(8, 32), 256, 0, stream>>>(AOb, Wob, bo, out);
}